// Round 1
// 127.833 us; speedup vs baseline: 1.0435x; 1.0435x over previous
//
#include <hip/hip_runtime.h>

#define IMG_W 512
#define IMG_H 512
#define PLANE_PX (IMG_W * IMG_H)
#define N_ELEMS (48 * PLANE_PX)
#define NTHREADS 256
#define TILEW 48
#define NCT 11                  // 10 full col-tiles + 1 partial (32 cols)
#define NBANDS 8                // 64-row bands
#define NBLK (48 * NBANDS * NCT)   // 4224

// 2*C1 and 2*C2 (the 0.25 scale factors cancel in num/den)
#define C1x2 2.0e-4f
#define C2x2 1.8e-3f

typedef _Float16 h2 __attribute__((ext_vector_type(2)));
typedef _Float16 h8 __attribute__((ext_vector_type(8)));
typedef float f32x4 __attribute__((ext_vector_type(4)));
typedef __fp16 fp16v2 __attribute__((ext_vector_type(2)));

// Packed f16 FMA (v_pk_fma_f16).
__device__ __forceinline__ h2 h2fma(_Float16 w, h2 v, h2 acc) {
    h2 wv = {w, w};
    return __builtin_elementwise_fma(wv, v, acc);
}
__device__ __forceinline__ unsigned int h2bits(h2 v) {
    union { h2 h; unsigned int u; } c; c.h = v; return c.u;
}
// v_cvt_pkrtz_f16_f32 returns __fp16x2; bit-cast to _Float16x2 (same layout).
__device__ __forceinline__ h2 pkrtz(float x, float y) {
    union { fp16v2 f; h2 h; } c;
    c.f = __builtin_amdgcn_cvt_pkrtz(x, y);
    return c.h;
}

__global__ void __launch_bounds__(NTHREADS, 5) ssim_main(
    const float* __restrict__ img1, const float* __restrict__ img2,
    float* __restrict__ partials)
{
    // Vertical-conv results, packed f16: R[row][col] = {(cs,cd),(css,cdd)}.
    // 64 rows x 64 cols x 8B = exactly 32 KiB -> 5 blocks/CU.
    // XOR swizzle col ^ ((row&7)<<1): keeps uint2 pairs contiguous (bit0
    // untouched) so b128 reads stay valid; spreads b128 reads to 2-way banks.
    __shared__ __align__(16) uint2 R[64 * 64];

    // Gaussian window (f16 taps for vertical conv).
    constexpr _Float16 Gh[11] = {
        (_Float16)0.00102838f, (_Float16)0.00759876f, (_Float16)0.03600077f,
        (_Float16)0.10936070f, (_Float16)0.21300553f, (_Float16)0.26601173f,
        (_Float16)0.21300553f, (_Float16)0.10936070f, (_Float16)0.03600077f,
        (_Float16)0.00759876f, (_Float16)0.00102838f
    };

    const int tid = threadIdx.x;

    // Work decode + XCD swizzle: XCD (blockIdx&7) owns 6 contiguous planes.
    const int xcd = blockIdx.x & 7;
    const int idx = blockIdx.x >> 3;             // [0,528)
    const int plane = xcd * 6 + idx / 88;
    const int t = idx % 88;
    const int band = t / 11;                     // y-band [0,8), 64 rows each
    const int ct = t - band * 11;                // col-tile [0,11)
    const int tx0 = ct * TILEW;
    const int ty0 = band * 64;
    const float* pa = img1 + (size_t)plane * PLANE_PX;
    const float* pb = img2 + (size_t)plane * PLANE_PX;

    // ================= Phase A: vertical conv, lane = staged column =========
    // 4 waves x 16 output rows each (26 staged rows, vs 2x18 before: -28%
    // redundant loads/pkrtz).
    const int c = tid & 63;                      // staged col
    const int g = tid >> 6;                      // wave = row-group
    const int gx = tx0 - 5 + c;
    const int cgx = min(max(gx, 0), IMG_W - 1);
    const int ry0 = ty0 + g * 16 - 5;

    float av[26], bv[26];
    const bool intY = (ry0 >= 0) && (ry0 + 26 <= IMG_H);     // wave-uniform
    if (intY) {
        const float* qa = pa + (size_t)ry0 * IMG_W + cgx;
        const float* qb = pb + (size_t)ry0 * IMG_W + cgx;
#pragma unroll
        for (int j = 0; j < 26; ++j) {
            av[j] = qa[j * IMG_W];
            bv[j] = qb[j * IMG_W];
        }
    } else {
#pragma unroll
        for (int j = 0; j < 26; ++j) {
            int ry = ry0 + j;
            int ryc = min(max(ry, 0), IMG_H - 1);
            float rm = ((unsigned)ry < (unsigned)IMG_H) ? 1.f : 0.f;
            av[j] = pa[(size_t)ryc * IMG_W + cgx] * rm;
            bv[j] = pb[(size_t)ryc * IMG_W + cgx] * rm;
        }
    }

    h2 asd[16], asq[16];
#pragma unroll
    for (int k = 0; k < 16; ++k) { asd[k] = (h2)(_Float16)0; asq[k] = (h2)(_Float16)0; }
#pragma unroll
    for (int j = 0; j < 26; ++j) {
        // (s,d) packed to f16 in ONE inst (v_cvt_pkrtz_f16_f32).
        h2 sd = pkrtz(av[j] + bv[j], av[j] - bv[j]);
        h2 sq = sd * sd;                         // v_pk_mul_f16
#pragma unroll
        for (int k = 0; k < 16; ++k) {
            int tt = j - k;
            if (tt >= 0 && tt < 11) {            // folds at compile time
                asd[k] = h2fma(Gh[tt], sd, asd[k]);
                asq[k] = h2fma(Gh[tt], sq, asq[k]);
            }
        }
    }

    // Column mask only needed for the edge col-tiles (wave-uniform branch).
    if (ct == 0 || ct == NCT - 1) {
        const _Float16 ml = ((unsigned)gx < (unsigned)IMG_W) ? (_Float16)1.f
                                                             : (_Float16)0.f;
        const h2 mlv = {ml, ml};
#pragma unroll
        for (int k = 0; k < 16; ++k) { asd[k] = asd[k] * mlv; asq[k] = asq[k] * mlv; }
    }
#pragma unroll
    for (int kk = 0; kk < 16; ++kk) {
        const int row = g * 16 + kk;             // row&7 == kk&7 (g*16 % 16 == 0)
        const int sc = c ^ ((kk & 7) << 1);      // swizzled physical col
        R[row * 64 + sc] = make_uint2(h2bits(asd[kk]), h2bits(asq[kk]));
    }
    __syncthreads();

    // ================= Phase B: horizontal conv via MFMA + SSIM =============
    // D[m][n] = sum_k A[m][k]*B[k][n], one mfma_f32_16x16x32_f16 per signal:
    //   m = output col in 16-col group, k = staged col in 32-window (band
    //   G[k-m], k-m in [0,11), max k = 25 < 32), n = image row slot.
    // A operand (lane l): m = l&15, k = (l>>4)*8 + j  -> constant band frag.
    // B operand (lane l): n = l&15, k = (l>>4)*8 + j  -> 4x ds_read_b128.
    // D (verified layout): n = l&15, m = (l>>4)*4 + reg -> f32, no cvts.
    const int lane = tid & 63;
    const int nrow = lane & 15;
    const int khi = lane >> 4;
    const int rs = tid >> 6;                     // wave = 16-row set
    const int row_lds = rs * 16 + nrow;
    const int swz = (nrow & 7) << 1;             // row_lds&7 == nrow&7
    const uint2* Rrow = R + row_lds * 64;

    // Build the constant Gaussian band A-fragment once (symmetric-tap select
    // chain + 8 wave shuffles; lanes >= 11 hold 0 so out-of-band taps are 0).
    int sidx = min(lane, 10 - lane);             // < 0 for lane > 10
    unsigned gvb = 0u;
    gvb = (sidx == 0) ? 0x1436u : gvb;           // f16 bits of G[0]
    gvb = (sidx == 1) ? 0x1FC8u : gvb;
    gvb = (sidx == 2) ? 0x289Cu : gvb;
    gvb = (sidx == 3) ? 0x2F00u : gvb;
    gvb = (sidx == 4) ? 0x32D1u : gvb;
    gvb = (sidx == 5) ? 0x3442u : gvb;           // f16 bits of G[5]
    union { h8 h; unsigned u[4]; } af;
#pragma unroll
    for (int w = 0; w < 4; ++w) {
        int t0 = khi * 8 + 2 * w - nrow;         // k - m for frag elems 2w,2w+1
        unsigned lo = (unsigned)__shfl((int)gvb, t0 & 63, 64);
        unsigned hi = (unsigned)__shfl((int)gvb, (t0 + 1) & 63, 64);
        af.u[w] = (lo & 0xFFFFu) | (hi << 16);
    }

    float local = 0.f;
#pragma unroll
    for (int mg = 0; mg < 3; ++mg) {
        if (tx0 + mg * 16 < IMG_W) {             // partial tile skips mg=2
            const int cb = mg * 16 + khi * 8;    // even; swz even -> pairs stay
            const uint4 q0 = *(const uint4*)&Rrow[(cb + 0) ^ swz];
            const uint4 q1 = *(const uint4*)&Rrow[(cb + 2) ^ swz];
            const uint4 q2 = *(const uint4*)&Rrow[(cb + 4) ^ swz];
            const uint4 q3 = *(const uint4*)&Rrow[(cb + 6) ^ swz];

            // De-interleave packed {(s,d),(ss,dd)} into 4 per-signal frags.
            union { h8 h; unsigned u[4]; } fs, fd, fss, fdd;
            fs.u[0]  = (q0.x & 0xFFFFu) | (q0.z << 16);
            fs.u[1]  = (q1.x & 0xFFFFu) | (q1.z << 16);
            fs.u[2]  = (q2.x & 0xFFFFu) | (q2.z << 16);
            fs.u[3]  = (q3.x & 0xFFFFu) | (q3.z << 16);
            fd.u[0]  = (q0.x >> 16) | (q0.z & 0xFFFF0000u);
            fd.u[1]  = (q1.x >> 16) | (q1.z & 0xFFFF0000u);
            fd.u[2]  = (q2.x >> 16) | (q2.z & 0xFFFF0000u);
            fd.u[3]  = (q3.x >> 16) | (q3.z & 0xFFFF0000u);
            fss.u[0] = (q0.y & 0xFFFFu) | (q0.w << 16);
            fss.u[1] = (q1.y & 0xFFFFu) | (q1.w << 16);
            fss.u[2] = (q2.y & 0xFFFFu) | (q2.w << 16);
            fss.u[3] = (q3.y & 0xFFFFu) | (q3.w << 16);
            fdd.u[0] = (q0.y >> 16) | (q0.w & 0xFFFF0000u);
            fdd.u[1] = (q1.y >> 16) | (q1.w & 0xFFFF0000u);
            fdd.u[2] = (q2.y >> 16) | (q2.w & 0xFFFF0000u);
            fdd.u[3] = (q3.y >> 16) | (q3.w & 0xFFFF0000u);

            const f32x4 z = {0.f, 0.f, 0.f, 0.f};
            f32x4 aS  = __builtin_amdgcn_mfma_f32_16x16x32_f16(af.h, fs.h,  z, 0, 0, 0);
            f32x4 aD  = __builtin_amdgcn_mfma_f32_16x16x32_f16(af.h, fd.h,  z, 0, 0, 0);
            f32x4 aSS = __builtin_amdgcn_mfma_f32_16x16x32_f16(af.h, fss.h, z, 0, 0, 0);
            f32x4 aDD = __builtin_amdgcn_mfma_f32_16x16x32_f16(af.h, fdd.h, z, 0, 0, 0);

            // Every computed pixel here is valid: no masks needed.
            // num/den share the 0.25 factor -> cancelled; constants are 2*C.
#pragma unroll
            for (int i = 0; i < 4; ++i) {
                float cs = aS[i], cd = aD[i], css = aSS[i], cdd = aDD[i];
                float P = cs * cs, Q = cd * cd;
                float U = P - Q;                 // 4*mu1*mu2
                float V = P + Q;                 // 2*(mu1^2+mu2^2)
                float num = (U + C1x2) * ((css - cdd) - U + C2x2);
                float den = (V + C1x2) * ((css + cdd) - V + C2x2);
                local += num * __builtin_amdgcn_rcpf(den);
            }
        }
    }

    // ================= Block reduction -> one partial ========================
#pragma unroll
    for (int off = 32; off > 0; off >>= 1) local += __shfl_down(local, off, 64);
    __syncthreads();                             // all R reads done: safe alias
    float* wp = (float*)R;
    if (lane == 0) wp[rs] = local;
    __syncthreads();
    if (tid == 0)
        partials[blockIdx.x] = wp[0] + wp[1] + wp[2] + wp[3];
}

__global__ void ssim_final(const float* __restrict__ partials,
                           float* __restrict__ out)
{
    __shared__ float wp[4];
    const int tid = threadIdx.x;
    const float4* p4 = (const float4*)partials;  // 4224/4 = 1056 float4
    float s = 0.f;
    for (int i = tid; i < NBLK / 4; i += NTHREADS) {
        float4 v = p4[i];
        s += (v.x + v.y) + (v.z + v.w);
    }
#pragma unroll
    for (int off = 32; off > 0; off >>= 1) s += __shfl_down(s, off, 64);
    if ((tid & 63) == 0) wp[tid >> 6] = s;
    __syncthreads();
    if (tid == 0)
        out[0] = 1.0f - (wp[0] + wp[1] + wp[2] + wp[3]) * (1.0f / (float)N_ELEMS);
}

extern "C" void kernel_launch(void* const* d_in, const int* in_sizes, int n_in,
                              void* d_out, int out_size, void* d_ws, size_t ws_size,
                              hipStream_t stream) {
    const float* img1 = (const float*)d_in[0];
    const float* img2 = (const float*)d_in[1];
    float* out = (float*)d_out;
    float* partials = (float*)d_ws;     // NBLK floats = 16.9 KB

    ssim_main<<<NBLK, NTHREADS, 0, stream>>>(img1, img2, partials);
    ssim_final<<<1, NTHREADS, 0, stream>>>(partials, out);
}